// Round 1
// baseline (2796.898 us; speedup 1.0000x reference)
//
#include <hip/hip_runtime.h>

namespace {
constexpr int D  = 48;
constexpr int D4 = 24;
constexpr int S2 = D * D4;        // 1152
constexpr int S1 = D * S2;        // 55296
constexpr int SC = D * S1;        // 2654208
constexpr int NB = 2;
constexpr int NELEM = NB * 3 * SC; // 15925248 floats per (B,3,48,48,48,24) tensor
}

__device__ __forceinline__ void load_line24(const float* __restrict__ p, float* v) {
    const float4* p4 = (const float4*)p;
#pragma unroll
    for (int q = 0; q < 6; ++q) {
        float4 f = p4[q];
        v[4*q+0] = f.x; v[4*q+1] = f.y; v[4*q+2] = f.z; v[4*q+3] = f.w;
    }
}

// Stage A: gather conv. in = concat(prev, bondary) -> 6 channels, 3x3x3x3 kernel, pad (1,1,1,1).
// Thread = (b, co, x1, x2, x3); computes the full 24-wide D4 line.
__global__ __launch_bounds__(256) void convA(
        const float* __restrict__ prev, const float* __restrict__ bnd,
        const float* __restrict__ Wg, const float* __restrict__ bg,
        float* __restrict__ dst)
{
    int t = blockIdx.x * 256 + threadIdx.x;
    int x3 = t % D; int r = t / D;
    int x2 = r % D; r /= D;
    int x1 = r % D; r /= D;
    int co = r % 3; int b  = r / 3;   // co,b uniform per block (48^3 % 256 == 0)

    float bias = bg[co];
    float acc[D4];
#pragma unroll
    for (int j = 0; j < D4; ++j) acc[j] = bias;

#pragma unroll 1
    for (int ci = 0; ci < 6; ++ci) {
        const float* src = (ci < 3) ? (prev + (b*3 + ci) * (size_t)SC)
                                    : (bnd  + (b*3 + ci - 3) * (size_t)SC);
        const float* wci = Wg + co * 486 + ci * 81;   // Wg[l]: (3,6,3,3,3,3)
#pragma unroll 1
        for (int k1 = 0; k1 < 3; ++k1) {
            int z1 = x1 + k1 - 1;
            if ((unsigned)z1 >= (unsigned)D) continue;
            const float* src1 = src + z1 * S1;
#pragma unroll
            for (int k2 = 0; k2 < 3; ++k2) {
                int z2 = x2 + k2 - 1;
                if ((unsigned)z2 >= (unsigned)D) continue;
#pragma unroll
                for (int k3 = 0; k3 < 3; ++k3) {
                    int z3 = x3 + k3 - 1;
                    if ((unsigned)z3 >= (unsigned)D) continue;
                    float v[26];
                    v[0] = 0.f; v[25] = 0.f;
                    load_line24(src1 + z2 * S2 + z3 * D4, v + 1);
                    const float* w = wci + k1*27 + k2*9 + k3*3;
                    float w0 = w[0], w1 = w[1], w2 = w[2];
#pragma unroll
                    for (int j = 0; j < D4; ++j)
                        acc[j] += w0*v[j] + w1*v[j+1] + w2*v[j+2];
                }
            }
        }
    }

    float4* o4 = (float4*)(dst + (size_t)t * D4);
#pragma unroll
    for (int q = 0; q < 6; ++q)
        o4[q] = make_float4(acc[4*q], acc[4*q+1], acc[4*q+2], acc[4*q+3]);
}

// Stage B+C fused: t2 = conv(t1, W1 (3,3,3,1), pad (1,1,1,0)) + b1, kept in regs for all 3 co;
// out = conv(t2, W2 (1,1,1,3), pad (0,0,0,1)) + b2 + conv(prev, Wd 1x1) + bd.
// Thread = (b, x1, x2, x3); computes all 3 channels of the 24-wide line.
__global__ __launch_bounds__(256) void convBC(
        const float* __restrict__ t1, const float* __restrict__ prev,
        const float* __restrict__ W1, const float* __restrict__ b1,
        const float* __restrict__ W2, const float* __restrict__ b2,
        const float* __restrict__ Wd, const float* __restrict__ bd,
        float* __restrict__ dst)
{
    int t = blockIdx.x * 256 + threadIdx.x;
    int x3 = t % D; int r = t / D;
    int x2 = r % D; r /= D;
    int x1 = r % D; int b = r / D;

    int spos = x1 * S1 + x2 * S2 + x3 * D4;

    float t2[3][D4];
#pragma unroll
    for (int c = 0; c < 3; ++c) {
        float bb = b1[c];
#pragma unroll
        for (int j = 0; j < D4; ++j) t2[c][j] = bb;
    }

#pragma unroll 1
    for (int ci = 0; ci < 3; ++ci) {
        const float* src = t1 + (b*3 + ci) * (size_t)SC;
#pragma unroll 1
        for (int k1 = 0; k1 < 3; ++k1) {
            int z1 = x1 + k1 - 1;
            if ((unsigned)z1 >= (unsigned)D) continue;
            const float* src1 = src + z1 * S1;
#pragma unroll
            for (int k2 = 0; k2 < 3; ++k2) {
                int z2 = x2 + k2 - 1;
                if ((unsigned)z2 >= (unsigned)D) continue;
#pragma unroll
                for (int k3 = 0; k3 < 3; ++k3) {
                    int z3 = x3 + k3 - 1;
                    if ((unsigned)z3 >= (unsigned)D) continue;
                    float v[D4];
                    load_line24(src1 + z2 * S2 + z3 * D4, v);
                    int kk = k1*9 + k2*3 + k3;
                    // W1[l]: (3,3,3,3,3,1) -> co*81 + ci*27 + kk
                    float wA = W1[  0 + ci*27 + kk];
                    float wB = W1[ 81 + ci*27 + kk];
                    float wC = W1[162 + ci*27 + kk];
#pragma unroll
                    for (int j = 0; j < D4; ++j) {
                        t2[0][j] += wA * v[j];
                        t2[1][j] += wB * v[j];
                        t2[2][j] += wC * v[j];
                    }
                }
            }
        }
    }

    // Stage C: (1,1,1,3) conv along D4 on in-register t2 + pointwise residual.
#pragma unroll 1
    for (int co = 0; co < 3; ++co) {
        float o[D4];
        float bb = b2[co] + bd[co];
#pragma unroll
        for (int j = 0; j < D4; ++j) o[j] = bb;
#pragma unroll
        for (int ci = 0; ci < 3; ++ci) {
            // W2[l]: (3,3,1,1,1,3) -> co*9 + ci*3 + k4
            float u0 = W2[co*9 + ci*3 + 0];
            float u1 = W2[co*9 + ci*3 + 1];
            float u2 = W2[co*9 + ci*3 + 2];
#pragma unroll
            for (int j = 0; j < D4; ++j) {
                float s = u1 * t2[ci][j];
                if (j > 0)  s += u0 * t2[ci][j-1];
                if (j < 23) s += u2 * t2[ci][j+1];
                o[j] += s;
            }
            float wd = Wd[co*3 + ci];
            float pv[D4];
            load_line24(prev + (b*3 + ci) * (size_t)SC + spos, pv);
#pragma unroll
            for (int j = 0; j < D4; ++j) o[j] += wd * pv[j];
        }
        float4* o4 = (float4*)(dst + (b*3 + co) * (size_t)SC + spos);
#pragma unroll
        for (int q = 0; q < 6; ++q)
            o4[q] = make_float4(o[4*q], o[4*q+1], o[4*q+2], o[4*q+3]);
    }
}

extern "C" void kernel_launch(void* const* d_in, const int* in_sizes, int n_in,
                              void* d_out, int out_size, void* d_ws, size_t ws_size,
                              hipStream_t stream)
{
    const float* f   = (const float*)d_in[0];
    const float* bnd = (const float*)d_in[1];
    const float* Wg  = (const float*)d_in[2];   // (4,3,6,3,3,3,3) = 4*1458
    const float* bg  = (const float*)d_in[3];   // (4,3)
    const float* W1  = (const float*)d_in[4];   // (4,3,3,3,3,3,1) = 4*243
    const float* b1  = (const float*)d_in[5];
    const float* W2  = (const float*)d_in[6];   // (4,3,3,1,1,1,3) = 4*27
    const float* b2  = (const float*)d_in[7];
    const float* Wd  = (const float*)d_in[8];   // (4,3,3,1,1,1,1) = 4*9
    const float* bd  = (const float*)d_in[9];

    float* t1 = (float*)d_ws;                 // gather-conv output
    float* o0 = t1 + NELEM;                   // ping buffer; d_out is the pong buffer
    float* obuf[4] = { o0, (float*)d_out, o0, (float*)d_out };

    const float* prev = f;
    for (int l = 0; l < 4; ++l) {
        convA<<<dim3((NB*3*D*D*D)/256), dim3(256), 0, stream>>>(
            prev, bnd, Wg + l*1458, bg + l*3, t1);
        convBC<<<dim3((NB*D*D*D)/256), dim3(256), 0, stream>>>(
            t1, prev, W1 + l*243, b1 + l*3, W2 + l*27, b2 + l*3,
            Wd + l*9, bd + l*3, obuf[l]);
        prev = obuf[l];
    }
}

// Round 2
// 1946.292 us; speedup vs baseline: 1.4370x; 1.4370x over previous
//
#include <hip/hip_runtime.h>

namespace {
constexpr int D  = 48;
constexpr int D4 = 24;
constexpr int S2 = D * D4;        // 1152
constexpr int S1 = D * S2;        // 55296
constexpr int SC = D * S1;        // 2654208
constexpr int NB = 2;
constexpr int NELEM = NB * 3 * SC; // floats per (B,3,48,48,48,24) tensor
}

__device__ __forceinline__ void load_line24(const float* __restrict__ p, float* v) {
    const float4* p4 = (const float4*)p;
#pragma unroll
    for (int q = 0; q < 6; ++q) {
        float4 f = p4[q];
        v[4*q+0] = f.x; v[4*q+1] = f.y; v[4*q+2] = f.z; v[4*q+3] = f.w;
    }
}

// Stage A: gather conv. in = concat(prev, bondary) -> 6 channels, 3x3x3x3 kernel, pad (1,1,1,1).
// Thread = (b, x1, x2, x3); computes ALL 3 output channels of the 24-wide D4 line.
// One line load feeds 3co x 24j x 3tap = 216 FMAs; weights are wave-uniform -> SGPRs.
__global__ __launch_bounds__(256) void convA(
        const float* __restrict__ prev, const float* __restrict__ bnd,
        const float* __restrict__ Wg, const float* __restrict__ bg,
        float* __restrict__ dst)
{
    int t = blockIdx.x * 256 + threadIdx.x;
    int x3 = t % D; int r = t / D;
    int x2 = r % D; r /= D;
    int x1 = r % D; int b = r / D;     // x1,b uniform-ish; x3 varies in-wave

    float acc[3][D4];
#pragma unroll
    for (int c = 0; c < 3; ++c) {
        float bb = bg[c];
#pragma unroll
        for (int j = 0; j < D4; ++j) acc[c][j] = bb;
    }

#pragma unroll 1
    for (int ci = 0; ci < 6; ++ci) {
        const float* src = (ci < 3) ? (prev + (b*3 + ci) * (size_t)SC)
                                    : (bnd  + (b*3 + ci - 3) * (size_t)SC);
        const float* wci = Wg + ci * 81;   // Wg[l]: (3co,6ci,3,3,3,3); + co*486 below
#pragma unroll 1
        for (int k1 = 0; k1 < 3; ++k1) {
            int z1 = x1 + k1 - 1;
            if ((unsigned)z1 >= (unsigned)D) continue;
            const float* src1 = src + z1 * S1;
#pragma unroll
            for (int k2 = 0; k2 < 3; ++k2) {
                int z2 = x2 + k2 - 1;
                if ((unsigned)z2 >= (unsigned)D) continue;
#pragma unroll
                for (int k3 = 0; k3 < 3; ++k3) {
                    int z3 = x3 + k3 - 1;
                    if ((unsigned)z3 >= (unsigned)D) continue;
                    float v[26];
                    v[0] = 0.f; v[25] = 0.f;
                    load_line24(src1 + z2 * S2 + z3 * D4, v + 1);
                    const float* w = wci + k1*27 + k2*9 + k3*3;
#pragma unroll
                    for (int co = 0; co < 3; ++co) {
                        float w0 = w[co*486 + 0];
                        float w1 = w[co*486 + 1];
                        float w2 = w[co*486 + 2];
#pragma unroll
                        for (int j = 0; j < D4; ++j)
                            acc[co][j] += w0*v[j] + w1*v[j+1] + w2*v[j+2];
                    }
                }
            }
        }
    }

    int spos = x1 * S1 + x2 * S2 + x3 * D4;
#pragma unroll
    for (int co = 0; co < 3; ++co) {
        float4* o4 = (float4*)(dst + (b*3 + co) * (size_t)SC + spos);
#pragma unroll
        for (int q = 0; q < 6; ++q)
            o4[q] = make_float4(acc[co][4*q], acc[co][4*q+1], acc[co][4*q+2], acc[co][4*q+3]);
    }
}

// Stage B+C fused: t2 = conv(t1, W1 (3,3,3,1), pad (1,1,1,0)) + b1, kept in regs for all 3 co;
// out = conv(t2, W2 (1,1,1,3), pad (0,0,0,1)) + b2 + conv(prev, Wd 1x1) + bd.
__global__ __launch_bounds__(256) void convBC(
        const float* __restrict__ t1, const float* __restrict__ prev,
        const float* __restrict__ W1, const float* __restrict__ b1,
        const float* __restrict__ W2, const float* __restrict__ b2,
        const float* __restrict__ Wd, const float* __restrict__ bd,
        float* __restrict__ dst)
{
    int t = blockIdx.x * 256 + threadIdx.x;
    int x3 = t % D; int r = t / D;
    int x2 = r % D; r /= D;
    int x1 = r % D; int b = r / D;

    int spos = x1 * S1 + x2 * S2 + x3 * D4;

    float t2[3][D4];
#pragma unroll
    for (int c = 0; c < 3; ++c) {
        float bb = b1[c];
#pragma unroll
        for (int j = 0; j < D4; ++j) t2[c][j] = bb;
    }

#pragma unroll 1
    for (int ci = 0; ci < 3; ++ci) {
        const float* src = t1 + (b*3 + ci) * (size_t)SC;
#pragma unroll 1
        for (int k1 = 0; k1 < 3; ++k1) {
            int z1 = x1 + k1 - 1;
            if ((unsigned)z1 >= (unsigned)D) continue;
            const float* src1 = src + z1 * S1;
#pragma unroll
            for (int k2 = 0; k2 < 3; ++k2) {
                int z2 = x2 + k2 - 1;
                if ((unsigned)z2 >= (unsigned)D) continue;
#pragma unroll
                for (int k3 = 0; k3 < 3; ++k3) {
                    int z3 = x3 + k3 - 1;
                    if ((unsigned)z3 >= (unsigned)D) continue;
                    float v[D4];
                    load_line24(src1 + z2 * S2 + z3 * D4, v);
                    int kk = k1*9 + k2*3 + k3;
                    // W1[l]: (3,3,3,3,3,1) -> co*81 + ci*27 + kk
                    float wA = W1[  0 + ci*27 + kk];
                    float wB = W1[ 81 + ci*27 + kk];
                    float wC = W1[162 + ci*27 + kk];
#pragma unroll
                    for (int j = 0; j < D4; ++j) {
                        t2[0][j] += wA * v[j];
                        t2[1][j] += wB * v[j];
                        t2[2][j] += wC * v[j];
                    }
                }
            }
        }
    }

    // Stage C: (1,1,1,3) conv along D4 on in-register t2 + pointwise residual.
#pragma unroll 1
    for (int co = 0; co < 3; ++co) {
        float o[D4];
        float bb = b2[co] + bd[co];
#pragma unroll
        for (int j = 0; j < D4; ++j) o[j] = bb;
#pragma unroll
        for (int ci = 0; ci < 3; ++ci) {
            // W2[l]: (3,3,1,1,1,3) -> co*9 + ci*3 + k4
            float u0 = W2[co*9 + ci*3 + 0];
            float u1 = W2[co*9 + ci*3 + 1];
            float u2 = W2[co*9 + ci*3 + 2];
#pragma unroll
            for (int j = 0; j < D4; ++j) {
                float s = u1 * t2[ci][j];
                if (j > 0)  s += u0 * t2[ci][j-1];
                if (j < 23) s += u2 * t2[ci][j+1];
                o[j] += s;
            }
            float wd = Wd[co*3 + ci];
            float pv[D4];
            load_line24(prev + (b*3 + ci) * (size_t)SC + spos, pv);
#pragma unroll
            for (int j = 0; j < D4; ++j) o[j] += wd * pv[j];
        }
        float4* o4 = (float4*)(dst + (b*3 + co) * (size_t)SC + spos);
#pragma unroll
        for (int q = 0; q < 6; ++q)
            o4[q] = make_float4(o[4*q], o[4*q+1], o[4*q+2], o[4*q+3]);
    }
}

extern "C" void kernel_launch(void* const* d_in, const int* in_sizes, int n_in,
                              void* d_out, int out_size, void* d_ws, size_t ws_size,
                              hipStream_t stream)
{
    const float* f   = (const float*)d_in[0];
    const float* bnd = (const float*)d_in[1];
    const float* Wg  = (const float*)d_in[2];   // (4,3,6,3,3,3,3) = 4*1458
    const float* bg  = (const float*)d_in[3];   // (4,3)
    const float* W1  = (const float*)d_in[4];   // (4,3,3,3,3,3,1) = 4*243
    const float* b1  = (const float*)d_in[5];
    const float* W2  = (const float*)d_in[6];   // (4,3,3,1,1,1,3) = 4*27
    const float* b2  = (const float*)d_in[7];
    const float* Wd  = (const float*)d_in[8];   // (4,3,3,1,1,1,1) = 4*9
    const float* bd  = (const float*)d_in[9];

    float* t1 = (float*)d_ws;                 // gather-conv output
    float* o0 = t1 + NELEM;                   // ping buffer; d_out is the pong buffer
    float* obuf[4] = { o0, (float*)d_out, o0, (float*)d_out };

    const float* prev = f;
    for (int l = 0; l < 4; ++l) {
        convA<<<dim3((NB*D*D*D)/256), dim3(256), 0, stream>>>(
            prev, bnd, Wg + l*1458, bg + l*3, t1);
        convBC<<<dim3((NB*D*D*D)/256), dim3(256), 0, stream>>>(
            t1, prev, W1 + l*243, b1 + l*3, W2 + l*27, b2 + l*3,
            Wd + l*9, bd + l*3, obuf[l]);
        prev = obuf[l];
    }
}

// Round 3
// 1529.644 us; speedup vs baseline: 1.8285x; 1.2724x over previous
//
#include <hip/hip_runtime.h>

typedef _Float16 half2_t __attribute__((ext_vector_type(2)));

#if __has_builtin(__builtin_amdgcn_fdot2)
#define FDOT2(a, b, c) __builtin_amdgcn_fdot2((a), (b), (c), false)
#else
__device__ __forceinline__ float FDOT2(half2_t a, half2_t b, float c) {
    return c + (float)a.x * (float)b.x + (float)a.y * (float)b.y;
}
#endif

namespace {
constexpr int D  = 48;
constexpr int D4 = 24;
constexpr int S2 = D * D4;        // 1152
constexpr int S1 = D * S2;        // 55296
constexpr int SC = D * S1;        // 2654208 elems per channel volume
constexpr int NB = 2;
constexpr int NELEM = NB * 3 * SC;
constexpr int NPAIR_H2 = NB * 3 * SC;   // half2 elements in the pairs buffer
}

// ---------------- pack kernels (run once per launch, tiny/BW-bound) ----------

// Wg[l]: (3co, 6ci, 3,3,3, 3k4) fp32 -> pw[((l*3+p)*27 + k123)*9 + co*3 + k4] as half2
// pairing ci = (2p, 2p+1).
__global__ __launch_bounds__(256) void pack_weights(
        const float* __restrict__ Wg, half2_t* __restrict__ pw)
{
    int i = blockIdx.x * 256 + threadIdx.x;
    const int NTOT = 4 * 3 * 27 * 9;          // 2916
    if (i >= NTOT) return;
    int k4 = i % 3; int r = i / 3;
    int co = r % 3; r /= 3;
    int k123 = r % 27; r /= 27;
    int p = r % 3; int l = r / 3;
    int ciA = 2 * p, ciB = 2 * p + 1;
    // Wg flat: ((l*3+co)*6 + ci)*81 + k123*3 + k4
    float a = Wg[((l * 3 + co) * 6 + ciA) * 81 + k123 * 3 + k4];
    float b = Wg[((l * 3 + co) * 6 + ciB) * 81 + k123 * 3 + k4];
    pw[i] = half2_t{(_Float16)a, (_Float16)b};
}

// Build pairs buffer from (f, bnd): pair0=(f0,f1), pair1=(f2,bnd0), pair2=(bnd1,bnd2)
__global__ __launch_bounds__(256) void pack_init(
        const float* __restrict__ f, const float* __restrict__ bnd,
        half2_t* __restrict__ pairs)
{
    int i = blockIdx.x * 256 + threadIdx.x;   // each thread packs 4 consecutive z
    int plane = i / (SC / 4);
    int zz = (i % (SC / 4)) * 4;
    int b = plane / 3, p = plane % 3;
    const float* A; const float* Bc;
    if (p == 0)      { A = f   + (size_t)(b*3 + 0) * SC; Bc = f   + (size_t)(b*3 + 1) * SC; }
    else if (p == 1) { A = f   + (size_t)(b*3 + 2) * SC; Bc = bnd + (size_t)(b*3 + 0) * SC; }
    else             { A = bnd + (size_t)(b*3 + 1) * SC; Bc = bnd + (size_t)(b*3 + 2) * SC; }
    float4 a = *(const float4*)(A + zz);
    float4 c = *(const float4*)(Bc + zz);
    union { float4 f4; half2_t h[4]; } u;
    u.h[0] = half2_t{(_Float16)a.x, (_Float16)c.x};
    u.h[1] = half2_t{(_Float16)a.y, (_Float16)c.y};
    u.h[2] = half2_t{(_Float16)a.z, (_Float16)c.z};
    u.h[3] = half2_t{(_Float16)a.w, (_Float16)c.w};
    *(float4*)(pairs + (size_t)plane * SC + zz) = u.f4;
}

// ---------------- Stage A: gather conv via v_dot2_f32_f16 ---------------------
// Thread = (b,x1,x2,x3), computes 3 co x 24-wide line, fp32 accumulation.
__global__ __launch_bounds__(256) void convA(
        const half2_t* __restrict__ pairs, const half2_t* __restrict__ pw,
        const float* __restrict__ bg, float* __restrict__ dst)
{
    int t = blockIdx.x * 256 + threadIdx.x;
    int x3 = t % D; int r = t / D;
    int x2 = r % D; r /= D;
    int x1 = r % D; int b = r / D;

    float acc[3][D4];
#pragma unroll
    for (int c = 0; c < 3; ++c) {
        float bb = bg[c];
#pragma unroll
        for (int j = 0; j < D4; ++j) acc[c][j] = bb;
    }

#pragma unroll 1
    for (int p = 0; p < 3; ++p) {
        const half2_t* src = pairs + (size_t)(b*3 + p) * SC;
#pragma unroll 1
        for (int k1 = 0; k1 < 3; ++k1) {
            int z1 = x1 + k1 - 1;
            if ((unsigned)z1 >= (unsigned)D) continue;
            const half2_t* src1 = src + z1 * S1;
#pragma unroll
            for (int k2 = 0; k2 < 3; ++k2) {
                int z2 = x2 + k2 - 1;
                if ((unsigned)z2 >= (unsigned)D) continue;
#pragma unroll
                for (int k3 = 0; k3 < 3; ++k3) {
                    int z3 = x3 + k3 - 1;
                    if ((unsigned)z3 >= (unsigned)D) continue;
                    half2_t v[26];
                    v[0] = half2_t{0, 0}; v[25] = half2_t{0, 0};
                    const float4* L = (const float4*)(src1 + z2 * S2 + z3 * D4);
#pragma unroll
                    for (int q = 0; q < 6; ++q) {
                        union { float4 f4; half2_t h[4]; } u;
                        u.f4 = L[q];
                        v[1 + 4*q + 0] = u.h[0];
                        v[1 + 4*q + 1] = u.h[1];
                        v[1 + 4*q + 2] = u.h[2];
                        v[1 + 4*q + 3] = u.h[3];
                    }
                    const half2_t* w = pw + (size_t)((p * 27 + (k1*9 + k2*3 + k3)) * 9);
#pragma unroll
                    for (int co = 0; co < 3; ++co) {
                        half2_t w0 = w[co*3 + 0];
                        half2_t w1 = w[co*3 + 1];
                        half2_t w2 = w[co*3 + 2];
#pragma unroll
                        for (int j = 0; j < D4; ++j) {
                            float a = acc[co][j];
                            a = FDOT2(w0, v[j],     a);
                            a = FDOT2(w1, v[j + 1], a);
                            a = FDOT2(w2, v[j + 2], a);
                            acc[co][j] = a;
                        }
                    }
                }
            }
        }
    }

    int spos = x1 * S1 + x2 * S2 + x3 * D4;
#pragma unroll
    for (int co = 0; co < 3; ++co) {
        float4* o4 = (float4*)(dst + (b*3 + co) * (size_t)SC + spos);
#pragma unroll
        for (int q = 0; q < 6; ++q)
            o4[q] = make_float4(acc[co][4*q], acc[co][4*q+1], acc[co][4*q+2], acc[co][4*q+3]);
    }
}

// ---------------- Stage B+C fused -------------------------------------------
// t2 = conv(t1, W1 (3,3,3,1), pad(1,1,1,0)) + b1 (fp32, in regs, all 3 ch)
// out = conv(t2, W2 (1,1,1,3)) + b2 + conv(res_f16, Wd 1x1) + bd
// Residual input read from the f16 pairs buffer; outputs re-packed into pairs
// (pair0=(o0,o1), pair1=(o2, bnd0 passthrough)); final layer also stores fp32.
__global__ __launch_bounds__(256) void convBC(
        const float* __restrict__ t1, half2_t* pairs,
        const float* __restrict__ W1, const float* __restrict__ b1,
        const float* __restrict__ W2, const float* __restrict__ b2,
        const float* __restrict__ Wd, const float* __restrict__ bd,
        float* __restrict__ dstF32, int writeF32)
{
    int t = blockIdx.x * 256 + threadIdx.x;
    int x3 = t % D; int r = t / D;
    int x2 = r % D; r /= D;
    int x1 = r % D; int b = r / D;

    int spos = x1 * S1 + x2 * S2 + x3 * D4;

    float t2[3][D4];
#pragma unroll
    for (int c = 0; c < 3; ++c) {
        float bb = b1[c];
#pragma unroll
        for (int j = 0; j < D4; ++j) t2[c][j] = bb;
    }

#pragma unroll 1
    for (int ci = 0; ci < 3; ++ci) {
        const float* src = t1 + (b*3 + ci) * (size_t)SC;
#pragma unroll 1
        for (int k1 = 0; k1 < 3; ++k1) {
            int z1 = x1 + k1 - 1;
            if ((unsigned)z1 >= (unsigned)D) continue;
            const float* src1 = src + z1 * S1;
#pragma unroll
            for (int k2 = 0; k2 < 3; ++k2) {
                int z2 = x2 + k2 - 1;
                if ((unsigned)z2 >= (unsigned)D) continue;
#pragma unroll
                for (int k3 = 0; k3 < 3; ++k3) {
                    int z3 = x3 + k3 - 1;
                    if ((unsigned)z3 >= (unsigned)D) continue;
                    const float4* L = (const float4*)(src1 + z2 * S2 + z3 * D4);
                    float v[D4];
#pragma unroll
                    for (int q = 0; q < 6; ++q) {
                        float4 f4 = L[q];
                        v[4*q+0] = f4.x; v[4*q+1] = f4.y; v[4*q+2] = f4.z; v[4*q+3] = f4.w;
                    }
                    int kk = k1*9 + k2*3 + k3;
                    float wA = W1[  0 + ci*27 + kk];
                    float wB = W1[ 81 + ci*27 + kk];
                    float wC = W1[162 + ci*27 + kk];
#pragma unroll
                    for (int j = 0; j < D4; ++j) {
                        t2[0][j] += wA * v[j];
                        t2[1][j] += wB * v[j];
                        t2[2][j] += wC * v[j];
                    }
                }
            }
        }
    }

    // residual source + bnd0 passthrough from pairs
    half2_t* p0ptr = pairs + (size_t)(b*3 + 0) * SC + spos;
    half2_t* p1ptr = pairs + (size_t)(b*3 + 1) * SC + spos;
    half2_t rp0[D4], rp1[D4];
#pragma unroll
    for (int q = 0; q < 6; ++q) {
        union { float4 f4; half2_t h[4]; } u;
        u.f4 = ((const float4*)p0ptr)[q];
        rp0[4*q+0]=u.h[0]; rp0[4*q+1]=u.h[1]; rp0[4*q+2]=u.h[2]; rp0[4*q+3]=u.h[3];
        u.f4 = ((const float4*)p1ptr)[q];
        rp1[4*q+0]=u.h[0]; rp1[4*q+1]=u.h[1]; rp1[4*q+2]=u.h[2]; rp1[4*q+3]=u.h[3];
    }

    // uniform weights for stage C
    float U[3][3][3];
#pragma unroll
    for (int co = 0; co < 3; ++co)
#pragma unroll
        for (int ci = 0; ci < 3; ++ci)
#pragma unroll
            for (int k = 0; k < 3; ++k)
                U[co][ci][k] = W2[co*9 + ci*3 + k];
    float WD[9];
#pragma unroll
    for (int i = 0; i < 9; ++i) WD[i] = Wd[i];
    float c0 = b2[0] + bd[0], c1 = b2[1] + bd[1], c2 = b2[2] + bd[2];

    float* d0 = dstF32 + (size_t)(b*3 + 0) * SC + spos;
    float* d1 = dstF32 + (size_t)(b*3 + 1) * SC + spos;
    float* d2 = dstF32 + (size_t)(b*3 + 2) * SC + spos;

#pragma unroll
    for (int j = 0; j < D4; ++j) {
        float s0 = c0, s1 = c1, s2 = c2;
#pragma unroll
        for (int ci = 0; ci < 3; ++ci) {
            float tm = (j > 0)  ? t2[ci][j-1] : 0.f;
            float tc = t2[ci][j];
            float tp = (j < 23) ? t2[ci][j+1] : 0.f;
            s0 += U[0][ci][0]*tm + U[0][ci][1]*tc + U[0][ci][2]*tp;
            s1 += U[1][ci][0]*tm + U[1][ci][1]*tc + U[1][ci][2]*tp;
            s2 += U[2][ci][0]*tm + U[2][ci][1]*tc + U[2][ci][2]*tp;
        }
        float pv0 = (float)rp0[j].x, pv1 = (float)rp0[j].y, pv2 = (float)rp1[j].x;
        s0 += WD[0]*pv0 + WD[1]*pv1 + WD[2]*pv2;
        s1 += WD[3]*pv0 + WD[4]*pv1 + WD[5]*pv2;
        s2 += WD[6]*pv0 + WD[7]*pv1 + WD[8]*pv2;
        p0ptr[j] = half2_t{(_Float16)s0, (_Float16)s1};
        p1ptr[j] = half2_t{(_Float16)s2, rp1[j].y};
        if (writeF32) { d0[j] = s0; d1[j] = s1; d2[j] = s2; }
    }
}

extern "C" void kernel_launch(void* const* d_in, const int* in_sizes, int n_in,
                              void* d_out, int out_size, void* d_ws, size_t ws_size,
                              hipStream_t stream)
{
    const float* f   = (const float*)d_in[0];
    const float* bnd = (const float*)d_in[1];
    const float* Wg  = (const float*)d_in[2];
    const float* bg  = (const float*)d_in[3];
    const float* W1  = (const float*)d_in[4];
    const float* b1  = (const float*)d_in[5];
    const float* W2  = (const float*)d_in[6];
    const float* b2  = (const float*)d_in[7];
    const float* Wd  = (const float*)d_in[8];
    const float* bd  = (const float*)d_in[9];

    float*   t1    = (float*)d_ws;                       // 64 MB fp32
    half2_t* pairs = (half2_t*)(t1 + NELEM);             // 64 MB f16 pairs
    // packed weights live in the tail of the pairs... need separate space:
    // place after pairs: 2916 half2 = 11.7 KB
    half2_t* pw    = pairs + NPAIR_H2;

    pack_weights<<<dim3((2916 + 255) / 256), dim3(256), 0, stream>>>(Wg, pw);
    pack_init<<<dim3(NB * 3 * (SC / 4) / 256), dim3(256), 0, stream>>>(f, bnd, pairs);

    const int grid = NB * D * D * D / 256;   // 864
    for (int l = 0; l < 4; ++l) {
        convA<<<dim3(grid), dim3(256), 0, stream>>>(pairs, pw + l * 729, bg + l*3, t1);
        convBC<<<dim3(grid), dim3(256), 0, stream>>>(
            t1, pairs, W1 + l*243, b1 + l*3, W2 + l*27, b2 + l*3,
            Wd + l*9, bd + l*3, (float*)d_out, l == 3 ? 1 : 0);
    }
}

// Round 4
// 1064.217 us; speedup vs baseline: 2.6281x; 1.4373x over previous
//
#include <hip/hip_runtime.h>

typedef _Float16 half2_t __attribute__((ext_vector_type(2)));

#if __has_builtin(__builtin_amdgcn_fdot2)
#define FDOT2(a, b, c) __builtin_amdgcn_fdot2((a), (b), (c), false)
#else
__device__ __forceinline__ float FDOT2(half2_t a, half2_t b, float c) {
    return c + (float)a.x * (float)b.x + (float)a.y * (float)b.y;
}
#endif

namespace {
constexpr int D  = 48;
constexpr int D4 = 24;
constexpr int S2 = D * D4;        // 1152
constexpr int S1 = D * S2;        // 55296
constexpr int SC = D * S1;        // 2654208 elems per channel volume
constexpr int NB = 2;
constexpr int NELEM = NB * 3 * SC;
constexpr int NPAIR_H2 = NB * 3 * SC;   // half2 elements in the pairs buffer
}

// ---------------- pack kernels (run once per launch, tiny/BW-bound) ----------

// Wg[l]: (3co, 6ci, 3,3,3, 3k4) fp32 -> pw[((l*3+p)*27 + k123)*9 + co*3 + k4] as half2
__global__ __launch_bounds__(256) void pack_weights(
        const float* __restrict__ Wg, half2_t* __restrict__ pw)
{
    int i = blockIdx.x * 256 + threadIdx.x;
    const int NTOT = 4 * 3 * 27 * 9;          // 2916
    if (i >= NTOT) return;
    int k4 = i % 3; int r = i / 3;
    int co = r % 3; r /= 3;
    int k123 = r % 27; r /= 27;
    int p = r % 3; int l = r / 3;
    int ciA = 2 * p, ciB = 2 * p + 1;
    float a = Wg[((l * 3 + co) * 6 + ciA) * 81 + k123 * 3 + k4];
    float b = Wg[((l * 3 + co) * 6 + ciB) * 81 + k123 * 3 + k4];
    pw[i] = half2_t{(_Float16)a, (_Float16)b};
}

// Build pairs buffer from (f, bnd): pair0=(f0,f1), pair1=(f2,bnd0), pair2=(bnd1,bnd2)
__global__ __launch_bounds__(256) void pack_init(
        const float* __restrict__ f, const float* __restrict__ bnd,
        half2_t* __restrict__ pairs)
{
    int i = blockIdx.x * 256 + threadIdx.x;   // each thread packs 4 consecutive z
    int plane = i / (SC / 4);
    int zz = (i % (SC / 4)) * 4;
    int b = plane / 3, p = plane % 3;
    const float* A; const float* Bc;
    if (p == 0)      { A = f   + (size_t)(b*3 + 0) * SC; Bc = f   + (size_t)(b*3 + 1) * SC; }
    else if (p == 1) { A = f   + (size_t)(b*3 + 2) * SC; Bc = bnd + (size_t)(b*3 + 0) * SC; }
    else             { A = bnd + (size_t)(b*3 + 1) * SC; Bc = bnd + (size_t)(b*3 + 2) * SC; }
    float4 a = *(const float4*)(A + zz);
    float4 c = *(const float4*)(Bc + zz);
    union { float4 f4; half2_t h[4]; } u;
    u.h[0] = half2_t{(_Float16)a.x, (_Float16)c.x};
    u.h[1] = half2_t{(_Float16)a.y, (_Float16)c.y};
    u.h[2] = half2_t{(_Float16)a.z, (_Float16)c.z};
    u.h[3] = half2_t{(_Float16)a.w, (_Float16)c.w};
    *(float4*)(pairs + (size_t)plane * SC + zz) = u.f4;
}

// ---------------- Stage A: gather conv via v_dot2_f32_f16 ---------------------
// Thread = (b,x1,x2,x3), computes 3 co x 24-wide line, fp32 accumulation.
// Output t1 stored as f16 (48 B/line), vectorized stores.
__global__ __launch_bounds__(256) void convA(
        const half2_t* __restrict__ pairs, const half2_t* __restrict__ pw,
        const float* __restrict__ bg, _Float16* __restrict__ dst)
{
    int t = blockIdx.x * 256 + threadIdx.x;
    int x3 = t % D; int r = t / D;
    int x2 = r % D; r /= D;
    int x1 = r % D; int b = r / D;

    float acc[3][D4];
#pragma unroll
    for (int c = 0; c < 3; ++c) {
        float bb = bg[c];
#pragma unroll
        for (int j = 0; j < D4; ++j) acc[c][j] = bb;
    }

#pragma unroll 1
    for (int p = 0; p < 3; ++p) {
        const half2_t* src = pairs + (size_t)(b*3 + p) * SC;
#pragma unroll 1
        for (int k1 = 0; k1 < 3; ++k1) {
            int z1 = x1 + k1 - 1;
            if ((unsigned)z1 >= (unsigned)D) continue;
            const half2_t* src1 = src + z1 * S1;
#pragma unroll
            for (int k2 = 0; k2 < 3; ++k2) {
                int z2 = x2 + k2 - 1;
                if ((unsigned)z2 >= (unsigned)D) continue;
#pragma unroll
                for (int k3 = 0; k3 < 3; ++k3) {
                    int z3 = x3 + k3 - 1;
                    if ((unsigned)z3 >= (unsigned)D) continue;
                    half2_t v[26];
                    v[0] = half2_t{0, 0}; v[25] = half2_t{0, 0};
                    const float4* L = (const float4*)(src1 + z2 * S2 + z3 * D4);
#pragma unroll
                    for (int q = 0; q < 6; ++q) {
                        union { float4 f4; half2_t h[4]; } u;
                        u.f4 = L[q];
                        v[1 + 4*q + 0] = u.h[0];
                        v[1 + 4*q + 1] = u.h[1];
                        v[1 + 4*q + 2] = u.h[2];
                        v[1 + 4*q + 3] = u.h[3];
                    }
                    const half2_t* w = pw + (size_t)((p * 27 + (k1*9 + k2*3 + k3)) * 9);
#pragma unroll
                    for (int co = 0; co < 3; ++co) {
                        half2_t w0 = w[co*3 + 0];
                        half2_t w1 = w[co*3 + 1];
                        half2_t w2 = w[co*3 + 2];
#pragma unroll
                        for (int j = 0; j < D4; ++j) {
                            float a = acc[co][j];
                            a = FDOT2(w0, v[j],     a);
                            a = FDOT2(w1, v[j + 1], a);
                            a = FDOT2(w2, v[j + 2], a);
                            acc[co][j] = a;
                        }
                    }
                }
            }
        }
    }

    int spos = x1 * S1 + x2 * S2 + x3 * D4;
#pragma unroll
    for (int co = 0; co < 3; ++co) {
        union { float4 f4[3]; _Float16 h[24]; } u;
#pragma unroll
        for (int j = 0; j < D4; ++j) u.h[j] = (_Float16)acc[co][j];
        float4* o4 = (float4*)(dst + (b*3 + co) * (size_t)SC + spos);
#pragma unroll
        for (int q = 0; q < 3; ++q) o4[q] = u.f4[q];
    }
}

// ---------------- Stage B+C fused -------------------------------------------
// t2 = conv(t1(f16), W1 (3,3,3,1), pad(1,1,1,0)) + b1 (fp32 accum, all 3 ch)
// out = conv(t2, W2 (1,1,1,3)) + b2 + conv(res_f16, Wd 1x1) + bd
// Outputs buffered in registers, then VECTORIZED float4 stores (pairs + optional fp32).
__global__ __launch_bounds__(256) void convBC(
        const _Float16* __restrict__ t1, half2_t* pairs,
        const float* __restrict__ W1, const float* __restrict__ b1,
        const float* __restrict__ W2, const float* __restrict__ b2,
        const float* __restrict__ Wd, const float* __restrict__ bd,
        float* __restrict__ dstF32, int writeF32)
{
    int t = blockIdx.x * 256 + threadIdx.x;
    int x3 = t % D; int r = t / D;
    int x2 = r % D; r /= D;
    int x1 = r % D; int b = r / D;

    int spos = x1 * S1 + x2 * S2 + x3 * D4;

    float t2[3][D4];
#pragma unroll
    for (int c = 0; c < 3; ++c) {
        float bb = b1[c];
#pragma unroll
        for (int j = 0; j < D4; ++j) t2[c][j] = bb;
    }

#pragma unroll 1
    for (int ci = 0; ci < 3; ++ci) {
        const _Float16* src = t1 + (b*3 + ci) * (size_t)SC;
#pragma unroll 1
        for (int k1 = 0; k1 < 3; ++k1) {
            int z1 = x1 + k1 - 1;
            if ((unsigned)z1 >= (unsigned)D) continue;
            const _Float16* src1 = src + z1 * S1;
#pragma unroll
            for (int k2 = 0; k2 < 3; ++k2) {
                int z2 = x2 + k2 - 1;
                if ((unsigned)z2 >= (unsigned)D) continue;
#pragma unroll
                for (int k3 = 0; k3 < 3; ++k3) {
                    int z3 = x3 + k3 - 1;
                    if ((unsigned)z3 >= (unsigned)D) continue;
                    const float4* L = (const float4*)(src1 + z2 * S2 + z3 * D4);
                    float v[D4];
#pragma unroll
                    for (int q = 0; q < 3; ++q) {
                        union { float4 f4; half2_t h[4]; } u;
                        u.f4 = L[q];
#pragma unroll
                        for (int m = 0; m < 4; ++m) {
                            v[8*q + 2*m + 0] = (float)u.h[m].x;
                            v[8*q + 2*m + 1] = (float)u.h[m].y;
                        }
                    }
                    int kk = k1*9 + k2*3 + k3;
                    float wA = W1[  0 + ci*27 + kk];
                    float wB = W1[ 81 + ci*27 + kk];
                    float wC = W1[162 + ci*27 + kk];
#pragma unroll
                    for (int j = 0; j < D4; ++j) {
                        t2[0][j] += wA * v[j];
                        t2[1][j] += wB * v[j];
                        t2[2][j] += wC * v[j];
                    }
                }
            }
        }
    }

    // residual source + bnd0 passthrough from pairs
    half2_t* p0ptr = pairs + (size_t)(b*3 + 0) * SC + spos;
    half2_t* p1ptr = pairs + (size_t)(b*3 + 1) * SC + spos;
    half2_t rp0[D4], rp1[D4];
#pragma unroll
    for (int q = 0; q < 6; ++q) {
        union { float4 f4; half2_t h[4]; } u;
        u.f4 = ((const float4*)p0ptr)[q];
        rp0[4*q+0]=u.h[0]; rp0[4*q+1]=u.h[1]; rp0[4*q+2]=u.h[2]; rp0[4*q+3]=u.h[3];
        u.f4 = ((const float4*)p1ptr)[q];
        rp1[4*q+0]=u.h[0]; rp1[4*q+1]=u.h[1]; rp1[4*q+2]=u.h[2]; rp1[4*q+3]=u.h[3];
    }

    float U[3][3][3];
#pragma unroll
    for (int co = 0; co < 3; ++co)
#pragma unroll
        for (int ci = 0; ci < 3; ++ci)
#pragma unroll
            for (int k = 0; k < 3; ++k)
                U[co][ci][k] = W2[co*9 + ci*3 + k];
    float WD[9];
#pragma unroll
    for (int i = 0; i < 9; ++i) WD[i] = Wd[i];
    float c0 = b2[0] + bd[0], c1 = b2[1] + bd[1], c2 = b2[2] + bd[2];

    float o0[D4], o1[D4], o2[D4];
#pragma unroll
    for (int j = 0; j < D4; ++j) {
        float s0 = c0, s1 = c1, s2 = c2;
#pragma unroll
        for (int ci = 0; ci < 3; ++ci) {
            float tm = (j > 0)  ? t2[ci][j-1] : 0.f;
            float tc = t2[ci][j];
            float tp = (j < 23) ? t2[ci][j+1] : 0.f;
            s0 += U[0][ci][0]*tm + U[0][ci][1]*tc + U[0][ci][2]*tp;
            s1 += U[1][ci][0]*tm + U[1][ci][1]*tc + U[1][ci][2]*tp;
            s2 += U[2][ci][0]*tm + U[2][ci][1]*tc + U[2][ci][2]*tp;
        }
        float pv0 = (float)rp0[j].x, pv1 = (float)rp0[j].y, pv2 = (float)rp1[j].x;
        s0 += WD[0]*pv0 + WD[1]*pv1 + WD[2]*pv2;
        s1 += WD[3]*pv0 + WD[4]*pv1 + WD[5]*pv2;
        s2 += WD[6]*pv0 + WD[7]*pv1 + WD[8]*pv2;
        o0[j] = s0; o1[j] = s1; o2[j] = s2;
    }

    // vectorized pair stores: plane0 = (o0,o1), plane1 = (o2, bnd0 passthrough)
    {
        union { float4 f4[6]; half2_t h[24]; } u0, u1;
#pragma unroll
        for (int j = 0; j < D4; ++j) {
            u0.h[j] = half2_t{(_Float16)o0[j], (_Float16)o1[j]};
            u1.h[j] = half2_t{(_Float16)o2[j], rp1[j].y};
        }
#pragma unroll
        for (int q = 0; q < 6; ++q) {
            ((float4*)p0ptr)[q] = u0.f4[q];
            ((float4*)p1ptr)[q] = u1.f4[q];
        }
    }

    if (writeF32) {
        float* d0 = dstF32 + (size_t)(b*3 + 0) * SC + spos;
        float* d1 = dstF32 + (size_t)(b*3 + 1) * SC + spos;
        float* d2 = dstF32 + (size_t)(b*3 + 2) * SC + spos;
#pragma unroll
        for (int q = 0; q < 6; ++q) {
            ((float4*)d0)[q] = make_float4(o0[4*q], o0[4*q+1], o0[4*q+2], o0[4*q+3]);
            ((float4*)d1)[q] = make_float4(o1[4*q], o1[4*q+1], o1[4*q+2], o1[4*q+3]);
            ((float4*)d2)[q] = make_float4(o2[4*q], o2[4*q+1], o2[4*q+2], o2[4*q+3]);
        }
    }
}

extern "C" void kernel_launch(void* const* d_in, const int* in_sizes, int n_in,
                              void* d_out, int out_size, void* d_ws, size_t ws_size,
                              hipStream_t stream)
{
    const float* f   = (const float*)d_in[0];
    const float* bnd = (const float*)d_in[1];
    const float* Wg  = (const float*)d_in[2];
    const float* bg  = (const float*)d_in[3];
    const float* W1  = (const float*)d_in[4];
    const float* b1  = (const float*)d_in[5];
    const float* W2  = (const float*)d_in[6];
    const float* b2  = (const float*)d_in[7];
    const float* Wd  = (const float*)d_in[8];
    const float* bd  = (const float*)d_in[9];

    _Float16* t1h   = (_Float16*)d_ws;                   // 32 MB f16
    half2_t*  pairs = (half2_t*)(t1h + NELEM);           // 64 MB f16 pairs
    half2_t*  pw    = pairs + NPAIR_H2;                  // 11.7 KB packed weights

    pack_weights<<<dim3((2916 + 255) / 256), dim3(256), 0, stream>>>(Wg, pw);
    pack_init<<<dim3(NB * 3 * (SC / 4) / 256), dim3(256), 0, stream>>>(f, bnd, pairs);

    const int grid = NB * D * D * D / 256;   // 864
    for (int l = 0; l < 4; ++l) {
        convA<<<dim3(grid), dim3(256), 0, stream>>>(pairs, pw + l * 729, bg + l*3, t1h);
        convBC<<<dim3(grid), dim3(256), 0, stream>>>(
            t1h, pairs, W1 + l*243, b1 + l*3, W2 + l*27, b2 + l*3,
            Wd + l*9, bd + l*3, (float*)d_out, l == 3 ? 1 : 0);
    }
}